// Round 12
// baseline (353.618 us; speedup 1.0000x reference)
//
#include <hip/hip_runtime.h>
#include <hip/hip_bf16.h>

// Problem constants (match reference)
#define TB   128          // batch B
#define NN   512          // nodes per graph
#define INC  128          // IN_C
#define HH   32           // HID
#define KP1  100          // K1
#define KP2  10           // K2
#define OC   10           // OUT_C
#define EPER 8192         // edges per graph
#define NT   (TB*NN)      // 65536 total nodes
#define ET   (TB*EPER)    // 1048576 total edges
#define ZTR  264          // gram ZT rows: 232 Z-cols + 32 zero pad (partial MFMA tiles)
#define ZTS  40           // ZT row stride in u16 (80 B, 16B-aligned for ds_read_b128)
#define XTS  136          // k_xw2 row stride in u16 (272 B, 16B-aligned)

typedef unsigned int  u32;
typedef unsigned short u16;
typedef __attribute__((ext_vector_type(8))) short bf16x8;   // 8 bf16 = 4 VGPR (MFMA A/B frag)
typedef __attribute__((ext_vector_type(16))) float f32x16;  // MFMA C/D frag

// bf16 helpers (RNE encode; exact decode)
__device__ __forceinline__ u32 bfr(float f) {
    u32 b = __float_as_uint(f);
    return (b + 0x7fffu + ((b >> 16) & 1u)) >> 16;
}
__device__ __forceinline__ u32 pk2(float a, float b) { return bfr(a) | (bfr(b) << 16); }
__device__ __forceinline__ float blo(u32 u) { return __uint_as_float(u << 16); }
__device__ __forceinline__ float bhi(u32 u) { return __uint_as_float(u & 0xffff0000u); }

// ---------------------------------------------------------------- init (aux only)
__global__ void k_init(float* __restrict__ aux) {
    int i = blockIdx.x * 256 + threadIdx.x;
    if (i < 1024) aux[i] = 0.0f;              // den1 / loss1 / loss2 accumulators
}

// ---- fused per-graph counting sort: histogram + scan + scatter + dis, all in LDS
__global__ __launch_bounds__(512) void k_sort(const int* __restrict__ ei,
                                              int* __restrict__ cnt_src, int* __restrict__ cnt_dst,
                                              int* __restrict__ off_src, int* __restrict__ off_dst,
                                              u16* __restrict__ srt_dst, u16* __restrict__ srt_src,
                                              float* __restrict__ dis) {
    __shared__ int hs[NN], hd[NN], ps[NN], pd[NN];              // 8 KB
    __shared__ __align__(16) u16 sdl[EPER], ssl[EPER];          // 32 KB
    int g = blockIdx.x, tid = threadIdx.x, goff = g * NN;
    hs[tid] = 0; hd[tid] = 0;
    __syncthreads();
    const int* es = ei + (size_t)g * EPER;
    const int* ed = ei + ET + (size_t)g * EPER;
    // pass 1: histograms
    for (int e = tid; e < EPER; e += 512) {
        atomicAdd(&hs[es[e] - goff], 1);
        atomicAdd(&hd[ed[e] - goff], 1);
    }
    __syncthreads();
    int vs = hs[tid], vd = hd[tid];
    ps[tid] = vs; pd[tid] = vd; __syncthreads();
    // Hillis-Steele inclusive scan of both histograms
    for (int off = 1; off < NN; off <<= 1) {
        int xa = ps[tid], xb = pd[tid];
        if (tid >= off) { xa += ps[tid - off]; xb += pd[tid - off]; }
        __syncthreads(); ps[tid] = xa; pd[tid] = xb; __syncthreads();
    }
    int eso = ps[tid] - vs, edo = pd[tid] - vd;   // exclusive offsets, graph-local
    cnt_src[goff + tid] = vs;  cnt_dst[goff + tid] = vd;
    off_src[goff + tid] = g * EPER + eso;
    off_dst[goff + tid] = g * EPER + edo;
    dis[goff + tid] = rsqrtf(1.0f + (float)vd);   // +1 self loop
    __syncthreads();
    ps[tid] = eso; pd[tid] = edo;                 // reuse as cursors
    __syncthreads();
    // pass 2: scatter into LDS (u16 local node ids)
    for (int e = tid; e < EPER; e += 512) {
        int s = es[e] - goff, d = ed[e] - goff;
        int p = atomicAdd(&ps[s], 1); sdl[p] = (u16)d;   // src-sorted: store dst
        int q = atomicAdd(&pd[d], 1); ssl[q] = (u16)s;   // dst-sorted: store src
    }
    __syncthreads();
    // coalesced write-out (u32 pairs)
    u32* wd = (u32*)(srt_dst + (size_t)g * EPER);
    u32* ws = (u32*)(srt_src + (size_t)g * EPER);
    const u32* rd = (const u32*)sdl;
    const u32* rs = (const u32*)ssl;
    for (int i = tid; i < EPER / 2; i += 512) { wd[i] = rd[i]; ws[i] = rs[i]; }
}

// ------- xw via MFMA: xw = bf16(x @ conv1_W), block = 128 rows, K=128
__global__ __launch_bounds__(256) void k_xw2(const float* __restrict__ x, const float* __restrict__ W,
                                             u16* __restrict__ xwb) {
    __shared__ u16 sX[128 * XTS];            // 34.8 KB
    __shared__ u16 sW[32 * XTS];             // 8.7 KB
    int tid = threadIdx.x;
    int nbase = blockIdx.x * 128;
    // stage W^T bf16: sW[n][k] = W[k*32+n]
    for (int i = tid; i < INC * HH; i += 256) {
        int k = i >> 5, n = i & 31;
        sW[n * XTS + k] = (u16)bfr(W[i]);
    }
    // stage x rows bf16 (coalesced float4 read, packed u32 LDS write)
    for (int i = tid; i < 128 * 32; i += 256) {
        int r = i >> 5, q = i & 31;
        float4 v = ((const float4*)(x + (size_t)(nbase + r) * INC))[q];
        u32* dst = (u32*)&sX[r * XTS + q * 4];
        dst[0] = pk2(v.x, v.y);
        dst[1] = pk2(v.z, v.w);
    }
    __syncthreads();
    int wave = tid >> 6, lane = tid & 63;
    int lc = lane & 31, half = lane >> 5;
    f32x16 acc;
#pragma unroll
    for (int r = 0; r < 16; r++) acc[r] = 0.f;
#pragma unroll
    for (int kc = 0; kc < 8; kc++) {
        bf16x8 af  = *(const bf16x8*)&sX[(wave * 32 + lc) * XTS + kc * 16 + half * 8];
        bf16x8 bfv = *(const bf16x8*)&sW[lc * XTS + kc * 16 + half * 8];
        acc = __builtin_amdgcn_mfma_f32_32x32x16_bf16(af, bfv, acc, 0, 0, 0);
    }
    // C/D: col n = lc, row m = (r&3)+8*(r>>2)+4*half
#pragma unroll
    for (int r = 0; r < 16; r++) {
        int m = (r & 3) + 8 * (r >> 2) + 4 * half;
        int rowg = nbase + wave * 32 + m;
        xwb[(size_t)rowg * HH + lc] = (u16)bfr(acc[r]);
    }
}

// -------- GCN gather v2: block = graph, xw slice + dis staged in LDS
__global__ __launch_bounds__(512) void k_gcng2(const u16* __restrict__ ssrc, const int* __restrict__ od,
                                               const int* __restrict__ cd, const u32* __restrict__ xwb32,
                                               const float* __restrict__ dis, const float* __restrict__ bias,
                                               u32* __restrict__ hb32) {
    __shared__ u32 sX[NN * 16];              // 32 KB (bf16 x2 per entry)
    __shared__ float sD[NN];                 // 2 KB
    int g = blockIdx.x, goff = g * NN, tid = threadIdx.x;
    for (int i = tid; i < NN * 16; i += 512) sX[i] = xwb32[(size_t)goff * 16 + i];
    if (tid < NN) sD[tid] = dis[goff + tid];
    __syncthreads();
    int wave = tid >> 6, lane = tid & 63;
    int sub = lane >> 4, cp = lane & 15;     // 4 nodes per wave, 16 lanes each
    float b0 = bias[2 * cp], b1 = bias[2 * cp + 1];
    for (int pass = 0; pass < 16; pass++) {
        int n = pass * 32 + wave * 4 + sub;
        int base = od[goff + n], cnt = cd[goff + n];
        const u16* idx = ssrc + base;
        float dn = sD[n];
        u32 us = sX[n * 16 + cp];
        float a0 = dn * blo(us), a1 = dn * bhi(us);
        int i = 0;
        for (; i + 4 <= cnt; i += 4) {
            int s0 = idx[i], s1v = idx[i + 1], s2 = idx[i + 2], s3 = idx[i + 3];
            float d0 = sD[s0], d1 = sD[s1v], d2 = sD[s2], d3 = sD[s3];
            u32 u0 = sX[s0 * 16 + cp], u1 = sX[s1v * 16 + cp];
            u32 u2 = sX[s2 * 16 + cp], u3 = sX[s3 * 16 + cp];
            a0 += d0 * blo(u0) + d1 * blo(u1) + d2 * blo(u2) + d3 * blo(u3);
            a1 += d0 * bhi(u0) + d1 * bhi(u1) + d2 * bhi(u2) + d3 * bhi(u3);
        }
        for (; i < cnt; i++) {
            int s0 = idx[i]; float d0 = sD[s0];
            u32 u0 = sX[s0 * 16 + cp];
            a0 += d0 * blo(u0); a1 += d0 * bhi(u0);
        }
        float v0 = fmaxf(dn * a0 + b0, 0.f);
        float v1 = fmaxf(dn * a1 + b1, 0.f);
        hb32[(size_t)(goff + n) * 16 + cp] = pk2(v0, v1);
    }
}

// ------- s1 via MFMA: logits = hb @ pool1_W + b, softmax in-register
__global__ __launch_bounds__(256) void k_s1m(const u32* __restrict__ hb32, const float* __restrict__ W,
                                             const float* __restrict__ bias, const int* __restrict__ csrc,
                                             u16* __restrict__ s1b, float* __restrict__ den1) {
    __shared__ u16 sH[128 * ZTS];            // 10.24 KB
    __shared__ u16 sW[128 * ZTS];            // 10.24 KB
    int tid = threadIdx.x;
    int nbase = blockIdx.x * 128;
    // stage W^T bf16: sW[n][k] = W[k*100+n]; coalesced read (n fastest)
    for (int i = tid; i < HH * KP1; i += 256) {
        int k = i / KP1, n = i - k * KP1;
        sW[n * ZTS + k] = (u16)bfr(W[i]);
    }
    // zero pad rows 100..127 (k 0..31 as 16 u32)
    for (int i = tid; i < 28 * 16; i += 256) {
        int n = 100 + (i >> 4), q = i & 15;
        ((u32*)sW)[n * (ZTS / 2) + q] = 0;
    }
    // stage hb rows (coalesced u32)
    for (int i = tid; i < 128 * 16; i += 256) {
        int r = i >> 4, q = i & 15;
        ((u32*)sH)[r * (ZTS / 2) + q] = hb32[(size_t)(nbase + r) * 16 + q];
    }
    __syncthreads();
    int wave = tid >> 6, lane = tid & 63;
    int lc = lane & 31, half = lane >> 5;
    f32x16 acc[4];
#pragma unroll
    for (int t = 0; t < 4; t++)
#pragma unroll
        for (int r = 0; r < 16; r++) acc[t][r] = 0.f;
#pragma unroll
    for (int kc = 0; kc < 2; kc++) {
        bf16x8 af = *(const bf16x8*)&sH[(wave * 32 + lc) * ZTS + kc * 16 + half * 8];
#pragma unroll
        for (int t = 0; t < 4; t++) {
            bf16x8 bfv = *(const bf16x8*)&sW[(t * 32 + lc) * ZTS + kc * 16 + half * 8];
            acc[t] = __builtin_amdgcn_mfma_f32_32x32x16_bf16(af, bfv, acc[t], 0, 0, 0);
        }
    }
    // bias + exp (overwrite acc with e); row sums via lc-butterfly
    float s[16], q[16];
#pragma unroll
    for (int r = 0; r < 16; r++) { s[r] = 0.f; q[r] = 0.f; }
#pragma unroll
    for (int t = 0; t < 4; t++) {
        int ch = t * 32 + lc;
        bool valid = ch < KP1;
        float bv = valid ? bias[ch] : 0.f;
#pragma unroll
        for (int r = 0; r < 16; r++) {
            float ev = valid ? __expf(acc[t][r] + bv) : 0.f;
            acc[t][r] = ev; s[r] += ev; q[r] = fmaf(ev, ev, q[r]);
        }
    }
#pragma unroll
    for (int off = 16; off >= 1; off >>= 1) {
#pragma unroll
        for (int r = 0; r < 16; r++) { s[r] += __shfl_xor(s[r], off); q[r] += __shfl_xor(q[r], off); }
    }
    float inv[16];
#pragma unroll
    for (int r = 0; r < 16; r++) inv[r] = 1.f / s[r];
    // store s1 bf16: row = (reg&3)+8*(reg>>2)+4*half (verified C/D layout), col = t*32+lc
#pragma unroll
    for (int t = 0; t < 4; t++) {
        int ch = t * 32 + lc;
        if (ch < KP1) {
#pragma unroll
            for (int r = 0; r < 16; r++) {
                int lr = (r & 3) + 8 * (r >> 2) + 4 * half;
                int rowg = nbase + wave * 32 + lr;
                s1b[(size_t)rowg * KP1 + ch] = (u16)bfr(acc[t][r] * inv[r]);
            }
        }
    }
    // den1: deg_out[row] * sum(s1^2) per row; lc==0 lanes hold replicated sums
    float contrib = 0.f;
    if (lc == 0) {
#pragma unroll
        for (int r = 0; r < 16; r++) {
            int lr = (r & 3) + 8 * (r >> 2) + 4 * half;
            int rowg = nbase + wave * 32 + lr;
            contrib += (float)csrc[rowg] * q[r] * inv[r] * inv[r];
        }
    }
    contrib += __shfl_xor(contrib, 32);
    if (lane == 0) atomicAdd(&den1[nbase >> 9], contrib);
}

// ------------- t1 gather v2: 2 blocks/graph (channel halves), s1 slice in LDS
__global__ __launch_bounds__(512) void k_t1g2(const u16* __restrict__ sdst, const int* __restrict__ osr,
                                              const int* __restrict__ csr, const u32* __restrict__ s1b32,
                                              u32* __restrict__ t1b32) {
    __shared__ u32 sS[NN * 25];              // 50 KB
    int g = blockIdx.x >> 1, half = blockIdx.x & 1;
    int goff = g * NN, coff = half * 25;
    int tid = threadIdx.x;
    for (int i = tid; i < NN * 25; i += 512) {
        int r = i / 25, q = i - r * 25;
        sS[i] = s1b32[(size_t)(goff + r) * 50 + coff + q];
    }
    __syncthreads();
    int wave = tid >> 6, lane = tid & 63;
    int sub = lane >> 5, l = lane & 31;      // 2 nodes per wave, lanes 0..24 active
    bool act = l < 25;
    for (int pass = 0; pass < 32; pass++) {
        int n = pass * 16 + wave * 2 + sub;
        int base = osr[goff + n], cnt = csr[goff + n];
        const u16* idx = sdst + base;
        float a0 = 0.f, a1 = 0.f;
        int i = 0;
        for (; i + 4 <= cnt; i += 4) {
            int d0 = idx[i], d1 = idx[i + 1], d2 = idx[i + 2], d3 = idx[i + 3];
            u32 u0 = sS[d0 * 25 + l], u1 = sS[d1 * 25 + l];
            u32 u2 = sS[d2 * 25 + l], u3 = sS[d3 * 25 + l];
            a0 += (blo(u0) + blo(u1)) + (blo(u2) + blo(u3));
            a1 += (bhi(u0) + bhi(u1)) + (bhi(u2) + bhi(u3));
        }
        for (; i < cnt; i++) {
            u32 u0 = sS[idx[i] * 25 + l];
            a0 += blo(u0); a1 += bhi(u0);
        }
        if (act) t1b32[(size_t)(goff + n) * 50 + coff + l] = pk2(a0, a1);
    }
}

// --- gram via MFMA: C = s1^T [t1 | h | s1] (100 x 232); bf16, 4 slabs.
__global__ __launch_bounds__(512, 4) void k_gram(const u32* __restrict__ s1b32, const u32* __restrict__ t1b32,
                                                 const u32* __restrict__ hb32, float* __restrict__ Cp) {
    __shared__ u16 sZ[2][ZTR * ZTS];         // 2 x 21.1 KB
    int g = blockIdx.x >> 2, slab = blockIdx.x & 3;
    int nbase = g * NN + slab * 128;         // 4 chunks of 32 rows
    int tid = threadIdx.x;
    int wave = tid >> 6, lane = tid & 63;
    int mt = wave & 3;                       // output-row tile: k = mt*32 + row
    int nt0 = (wave >> 2) * 4;               // this wave: nt0..nt0+3
    int lc = lane & 31, half = lane >> 5;

    f32x16 acc[4];
#pragma unroll
    for (int t = 0; t < 4; t++)
#pragma unroll
        for (int r = 0; r < 16; r++) acc[t][r] = 0.f;

    // zero the padding rows of both buffers (channels 232..263)
    for (int i = tid; i < 32 * ZTS; i += 512) {
        int r = 232 + i / ZTS, c = i % ZTS;
        sZ[0][r * ZTS + c] = 0; sZ[1][r * ZTS + c] = 0;
    }
    // ---- stage chunk 0 into buffer 0 (transposing: uint2 = 4 channels of row n)
#pragma unroll
    for (int j = 0; j < 4; j++) {
        int i = tid + j * 512;
        if (i < 32 * 58) {
            int r = i / 58, q = i - r * 58;
            int n = nbase + r;
            uint2 v; int ch0;
            if (q < 25)      { v = ((const uint2*)(t1b32 + (size_t)n * 50))[q];      ch0 = 4 * q; }
            else if (q < 33) { v = ((const uint2*)(hb32  + (size_t)n * 16))[q - 25]; ch0 = 100 + 4 * (q - 25); }
            else             { v = ((const uint2*)(s1b32 + (size_t)n * 50))[q - 33]; ch0 = 132 + 4 * (q - 33); }
            sZ[0][(ch0    ) * ZTS + r] = (u16)(v.x & 0xffffu);
            sZ[0][(ch0 + 1) * ZTS + r] = (u16)(v.x >> 16);
            sZ[0][(ch0 + 2) * ZTS + r] = (u16)(v.y & 0xffffu);
            sZ[0][(ch0 + 3) * ZTS + r] = (u16)(v.y >> 16);
        }
    }
    __syncthreads();

    for (int nt = 0; nt < 4; nt++) {
        // ---- prefetch chunk nt+1 into registers
        uint2 pre[4];
        if (nt < 3) {
#pragma unroll
            for (int j = 0; j < 4; j++) {
                int i = tid + j * 512;
                if (i < 32 * 58) {
                    int r = i / 58, q = i - r * 58;
                    int n = nbase + (nt + 1) * 32 + r;
                    uint2 v;
                    if (q < 25)      v = ((const uint2*)(t1b32 + (size_t)n * 50))[q];
                    else if (q < 33) v = ((const uint2*)(hb32  + (size_t)n * 16))[q - 25];
                    else             v = ((const uint2*)(s1b32 + (size_t)n * 50))[q - 33];
                    pre[j] = v;
                }
            }
        }
        // ---- MFMA on current buffer
        const u16* zb = sZ[nt & 1];
#pragma unroll
        for (int mf = 0; mf < 2; mf++) {
            bf16x8 af = *(const bf16x8*)&zb[(132 + mt * 32 + lc) * ZTS + mf * 16 + half * 8];
#pragma unroll
            for (int t = 0; t < 4; t++) {
                bf16x8 bfv = *(const bf16x8*)&zb[((nt0 + t) * 32 + lc) * ZTS + mf * 16 + half * 8];
                acc[t] = __builtin_amdgcn_mfma_f32_32x32x16_bf16(af, bfv, acc[t], 0, 0, 0);
            }
        }
        // ---- commit prefetch to the other buffer
        if (nt < 3) {
            u16* zo = sZ[(nt + 1) & 1];
#pragma unroll
            for (int j = 0; j < 4; j++) {
                int i = tid + j * 512;
                if (i < 32 * 58) {
                    int r = i / 58, q = i - r * 58;
                    int ch0 = (q < 25) ? (4 * q) : ((q < 33) ? (100 + 4 * (q - 25)) : (132 + 4 * (q - 33)));
                    zo[(ch0    ) * ZTS + r] = (u16)(pre[j].x & 0xffffu);
                    zo[(ch0 + 1) * ZTS + r] = (u16)(pre[j].x >> 16);
                    zo[(ch0 + 2) * ZTS + r] = (u16)(pre[j].y & 0xffffu);
                    zo[(ch0 + 3) * ZTS + r] = (u16)(pre[j].y >> 16);
                }
            }
        }
        __syncthreads();
    }
    // ---- epilogue: C/D layout col=lane&31, row=(reg&3)+8*(reg>>2)+4*(lane>>5)
    float* outp = Cp + ((size_t)slab * TB + g) * (KP1 * 232);
#pragma unroll
    for (int t = 0; t < 4; t++) {
        int l = (nt0 + t) * 32 + lc;
        if (l < 232) {
#pragma unroll
            for (int r = 0; r < 16; r++) {
                int k = mt * 32 + (r & 3) + 8 * (r >> 2) + 4 * half;
                if (k < KP1) outp[k * 232 + l] = acc[t][r];
            }
        }
    }
}

// ---- finalize stage 1: coalesced float4 slab sweep; losses; normalize; P1
__global__ __launch_bounds__(256) void k_fin1(const float* __restrict__ Cp, const float* __restrict__ den1,
                                              float* __restrict__ A1n, float* __restrict__ P1,
                                              float* __restrict__ aux) {
    __shared__ float sA[KP1 * KP1];          // 40 KB
    __shared__ float red[256];
    __shared__ float rs2[256];
    __shared__ float sdv[KP1];
    int g = blockIdx.x, tid = threadIdx.x;
    const float* b0 = Cp + (size_t)g * (KP1 * 232);
    const size_t SLAB = (size_t)TB * (KP1 * 232);
    float ssq = 0.f, trss = 0.f, troa = 0.f;
    // phase 1: sweep 100 rows x 58 float4 cols, coalesced; sum 4 slabs in flight
    for (int idx = tid; idx < KP1 * 58; idx += 256) {
        int k = idx / 58, q = idx - k * 58;
        size_t off = (size_t)k * 232 + q * 4;
        float4 v0 = *(const float4*)(b0 + off);
        float4 v1 = *(const float4*)(b0 + SLAB + off);
        float4 v2 = *(const float4*)(b0 + 2 * SLAB + off);
        float4 v3 = *(const float4*)(b0 + 3 * SLAB + off);
        float4 s;
        s.x = (v0.x + v1.x) + (v2.x + v3.x);
        s.y = (v0.y + v1.y) + (v2.y + v3.y);
        s.z = (v0.z + v1.z) + (v2.z + v3.z);
        s.w = (v0.w + v1.w) + (v2.w + v3.w);
        int c = q * 4;
        if (c < 100) {                        // out_adj block
            *(float4*)&sA[k * KP1 + c] = s;
            if (k >= c && k < c + 4) troa += ((const float*)&s)[k - c];
        } else if (c < 132) {                 // pooled features -> P1 direct
            *(float4*)&P1[((size_t)g * KP1 + k) * HH + (c - 100)] = s;
        } else {                              // ss block: reduce only
            ssq += s.x * s.x + s.y * s.y + s.z * s.z + s.w * s.w;
            int l0 = c - 132;
            if (k >= l0 && k < l0 + 4) trss += ((const float*)&s)[k - l0];
        }
    }
    // block reductions for ssq / trss / troa
    red[tid] = ssq; __syncthreads();
#pragma unroll
    for (int s = 128; s > 0; s >>= 1) { if (tid < s) red[tid] += red[tid + s]; __syncthreads(); }
    float ssqT = red[0]; __syncthreads();
    red[tid] = trss; __syncthreads();
#pragma unroll
    for (int s = 128; s > 0; s >>= 1) { if (tid < s) red[tid] += red[tid + s]; __syncthreads(); }
    float trssT = red[0]; __syncthreads();
    red[tid] = troa; __syncthreads();
#pragma unroll
    for (int s = 128; s > 0; s >>= 1) { if (tid < s) red[tid] += red[tid + s]; __syncthreads(); }
    float troaT = red[0]; __syncthreads();
    // phase 2: row sums (2 threads per row) -> sd
    if (tid < 200) {
        int k = tid >> 1, hf = tid & 1;
        const float* row = &sA[k * KP1 + hf * 50];
        float rs = 0.f;
        for (int l = 0; l < 50; l++) rs += row[l];
        rs2[tid] = rs;
    }
    __syncthreads();
    if (tid < KP1) {
        float rowsum = rs2[2 * tid] + rs2[2 * tid + 1] - sA[tid * KP1 + tid];
        sdv[tid] = sqrtf(rowsum) + 1e-15f;
    }
    if (tid == 0) {
        float ssF = sqrtf(ssqT);
        float o1 = sqrtf(fmaxf(2.f - 2.f * trssT / (ssF * 10.f), 0.f));  // sqrt(K1)=10
        aux[128 + g] = -(troaT / den1[g]) + o1;
    }
    __syncthreads();
    // phase 3: normalize out_adj, coalesced
    for (int i = tid; i < KP1 * KP1; i += 256) {
        int k = i / KP1, l = i - k * KP1;
        A1n[(size_t)g * (KP1 * KP1) + i] = (k == l) ? 0.f : sA[i] / (sdv[k] * sdv[l]);
    }
}

// ------- stage 2a: conv2 + pool2 (per graph); A read from global (L2)
__global__ __launch_bounds__(512) void k_s2a(const float* __restrict__ A1n, const float* __restrict__ P1,
                                             const float* __restrict__ relW, const float* __restrict__ relB,
                                             const float* __restrict__ rootW,
                                             const float* __restrict__ p2W, const float* __restrict__ p2B,
                                             float* __restrict__ P2, float* __restrict__ A2n,
                                             float* __restrict__ aux) {
    __shared__ float sX[KP1 * HH];           // x1p then x2
    __shared__ float sY[KP1 * HH];           // y = A @ x1p
    __shared__ float sS2[KP1 * KP2];
    __shared__ float sT2[KP1 * KP2];
    __shared__ float sA2[100], sB2[100], sdd[10], red[100];
    int g = blockIdx.x, tid = threadIdx.x;
    const float* Ag = A1n + (size_t)g * (KP1 * KP1);
    for (int i = tid; i < KP1 * HH; i += 512) sX[i] = P1[(size_t)g * (KP1 * HH) + i];
    __syncthreads();

    int n = tid >> 2, cq = tid & 3;          // 400 active threads for y / x2
    // y = A @ x1p
    if (tid < 400) {
        float yv[8];
#pragma unroll
        for (int j = 0; j < 8; j++) yv[j] = 0.f;
        for (int mq = 0; mq < 25; mq++) {
            float4 a4 = *(const float4*)&Ag[n * KP1 + mq * 4];
            const float* xb = &sX[(mq * 4) * HH + cq * 8];
            float aa[4] = {a4.x, a4.y, a4.z, a4.w};
#pragma unroll
            for (int mm = 0; mm < 4; mm++) {
                const float* xr = xb + mm * HH;
#pragma unroll
                for (int j = 0; j < 8; j++) yv[j] = fmaf(aa[mm], xr[j], yv[j]);
            }
        }
#pragma unroll
        for (int j = 0; j < 8; j++) sY[n * HH + cq * 8 + j] = yv[j];
    }
    __syncthreads();
    // x2 = relu(y @ relW + relB + x1p @ rootW)
    float x2v[8];
    if (tid < 400) {
#pragma unroll
        for (int j = 0; j < 8; j++) x2v[j] = relB[cq * 8 + j];
        for (int j = 0; j < 32; j++) {
            float yj = sY[n * HH + j];
            float xj = sX[n * HH + j];
            float4 r0 = *(const float4*)&relW[j * 32 + cq * 8];
            float4 r1v = *(const float4*)&relW[j * 32 + cq * 8 + 4];
            float4 q0 = *(const float4*)&rootW[j * 32 + cq * 8];
            float4 q1 = *(const float4*)&rootW[j * 32 + cq * 8 + 4];
            x2v[0] += yj * r0.x + xj * q0.x;  x2v[1] += yj * r0.y + xj * q0.y;
            x2v[2] += yj * r0.z + xj * q0.z;  x2v[3] += yj * r0.w + xj * q0.w;
            x2v[4] += yj * r1v.x + xj * q1.x; x2v[5] += yj * r1v.y + xj * q1.y;
            x2v[6] += yj * r1v.z + xj * q1.z; x2v[7] += yj * r1v.w + xj * q1.w;
        }
    }
    __syncthreads();
    if (tid < 400) {
#pragma unroll
        for (int j = 0; j < 8; j++) sX[n * HH + cq * 8 + j] = fmaxf(x2v[j], 0.f);
    }
    __syncthreads();
    // s2 = softmax(x2 @ p2W + p2B); d2 and den2 partials
    if (tid < KP1) {
        float lg[10];
#pragma unroll
        for (int j = 0; j < 10; j++) lg[j] = p2B[j];
        for (int c = 0; c < 32; c++) {
            float xv = sX[tid * HH + c];
#pragma unroll
            for (int j = 0; j < 10; j++) lg[j] = fmaf(xv, p2W[c * 10 + j], lg[j]);
        }
        float mx = lg[0];
#pragma unroll
        for (int j = 1; j < 10; j++) mx = fmaxf(mx, lg[j]);
        float se = 0.f;
#pragma unroll
        for (int j = 0; j < 10; j++) { lg[j] = __expf(lg[j] - mx); se += lg[j]; }
        float inv = 1.f / se, sq = 0.f;
#pragma unroll
        for (int j = 0; j < 10; j++) { float sv = lg[j] * inv; sS2[tid * 10 + j] = sv; sq += sv * sv; }
        float d2 = 0.f;
        for (int mq = 0; mq < 25; mq++) {
            float4 a4 = *(const float4*)&Ag[tid * KP1 + mq * 4];
            d2 += a4.x + a4.y + a4.z + a4.w;
        }
        red[tid] = d2 * sq;
    }
    __syncthreads();
    // t2 = A @ s2 ; P2 = s2^T x2
    for (int p = tid; p < KP1 * KP2; p += 512) {
        int n2 = p / 10, jj = p % 10;
        float a = 0.f;
        for (int m = 0; m < KP1; m++) a = fmaf(Ag[n2 * KP1 + m], sS2[m * 10 + jj], a);
        sT2[p] = a;
    }
    if (tid < KP2 * HH) {
        int k = tid >> 5, cc = tid & 31;
        float a = 0.f;
        for (int n2 = 0; n2 < KP1; n2++) a = fmaf(sS2[n2 * 10 + k], sX[n2 * HH + cc], a);
        P2[(size_t)g * (KP2 * HH) + tid] = a;
    }
    __syncthreads();
    // oa2, ss2
    if (tid < 100) {
        int k = tid / 10, l = tid % 10;
        float oa = 0.f, ss = 0.f;
        for (int n2 = 0; n2 < KP1; n2++) {
            float sk = sS2[n2 * 10 + k];
            oa = fmaf(sk, sT2[n2 * 10 + l], oa);
            ss = fmaf(sk, sS2[n2 * 10 + l], ss);
        }
        sA2[tid] = oa; sB2[tid] = ss;
    }
    __syncthreads();
    if (tid == 0) {
        float den2 = 0.f;
        for (int i = 0; i < 100; i++) den2 += red[i];
        float troa = 0.f, trss = 0.f, ssq = 0.f;
        for (int k = 0; k < 10; k++) { troa += sA2[k * 10 + k]; trss += sB2[k * 10 + k]; }
        for (int i = 0; i < 100; i++) ssq += sB2[i] * sB2[i];
        float o2 = sqrtf(fmaxf(2.f - 2.f * trss / (sqrtf(ssq) * 3.16227766f), 0.f)); // sqrt(10)
        aux[256 + g] = -(troa / den2) + o2;
    }
    if (tid < 10) {
        float rs = 0.f;
        for (int l = 0; l < 10; l++) if (l != tid) rs += sA2[tid * 10 + l];
        sdd[tid] = sqrtf(rs) + 1e-15f;
    }
    __syncthreads();
    if (tid < 100) {
        int k = tid / 10, l = tid % 10;
        A2n[(size_t)g * 100 + tid] = (k == l) ? 0.f : sA2[tid] / (sdd[k] * sdd[l]);
    }
}

// ---------------- stage 2b: conv3 + mean + MLP head + log_softmax
__global__ __launch_bounds__(64) void k_s2b(const float* __restrict__ P2, const float* __restrict__ A2n,
                                            const float* __restrict__ relW3, const float* __restrict__ relb3,
                                            const float* __restrict__ rootW3,
                                            const float* __restrict__ l1W, const float* __restrict__ l1b,
                                            const float* __restrict__ l2W, const float* __restrict__ l2b,
                                            float* __restrict__ out) {
    __shared__ float sP[KP2 * HH], sA2[100], sY3[KP2 * HH], sG[32], sG1[32], sL[10], sLse;
    int g = blockIdx.x, tid = threadIdx.x;
    for (int i = tid; i < KP2 * HH; i += 64) sP[i] = P2[(size_t)g * (KP2 * HH) + i];
    for (int i = tid; i < 100; i += 64) sA2[i] = A2n[(size_t)g * 100 + i];
    if (tid < 32) sG[tid] = 0.f;
    __syncthreads();
    for (int p = tid; p < KP2 * HH; p += 64) {
        int k = p >> 5, cc = p & 31;
        float a = 0.f;
#pragma unroll
        for (int m = 0; m < 10; m++) a = fmaf(sA2[k * 10 + m], sP[m * HH + cc], a);
        sY3[p] = a;
    }
    __syncthreads();
    for (int p = tid; p < KP2 * HH; p += 64) {
        int k = p >> 5, cc = p & 31;
        float v = relb3[cc];
        for (int j = 0; j < 32; j++)
            v += sY3[k * HH + j] * relW3[j * 32 + cc] + sP[k * HH + j] * rootW3[j * 32 + cc];
        atomicAdd(&sG[cc], v * 0.1f);        // mean over 10 nodes
    }
    __syncthreads();
    if (tid < 32) {
        float v = l1b[tid];
        for (int j = 0; j < 32; j++) v = fmaf(sG[j], l1W[j * 32 + tid], v);
        sG1[tid] = fmaxf(v, 0.f);
    }
    __syncthreads();
    if (tid < 10) {
        float v = l2b[tid];
        for (int j = 0; j < 32; j++) v = fmaf(sG1[j], l2W[j * 10 + tid], v);
        sL[tid] = v;
    }
    __syncthreads();
    if (tid == 0) {
        float mx = sL[0];
        for (int j = 1; j < 10; j++) mx = fmaxf(mx, sL[j]);
        float se = 0.f;
        for (int j = 0; j < 10; j++) se += expf(sL[j] - mx);
        sLse = mx + logf(se);
    }
    __syncthreads();
    if (tid < 10) out[(size_t)g * 10 + tid] = sL[tid] - sLse;
}

// ------------------------------------------------------ total loss
__global__ void k_loss(const float* __restrict__ aux, float* __restrict__ out) {
    __shared__ float red[128];
    int tid = threadIdx.x;
    red[tid] = aux[128 + tid] + aux[256 + tid];
    __syncthreads();
#pragma unroll
    for (int s = 64; s > 0; s >>= 1) { if (tid < s) red[tid] += red[tid + s]; __syncthreads(); }
    if (tid == 0) out[1280] = red[0] * (1.f / 128.f);
}

extern "C" void kernel_launch(void* const* d_in, const int* in_sizes, int n_in,
                              void* d_out, int out_size, void* d_ws, size_t ws_size,
                              hipStream_t stream) {
    const float* x    = (const float*)d_in[0];
    const int*   ei   = (const int*)d_in[1];
    const float* c1W  = (const float*)d_in[3];
    const float* c1b  = (const float*)d_in[4];
    const float* p1W  = (const float*)d_in[5];
    const float* p1b  = (const float*)d_in[6];
    const float* relW2  = (const float*)d_in[7];
    const float* relb2  = (const float*)d_in[8];
    const float* rootW2 = (const float*)d_in[9];
    const float* p2W  = (const float*)d_in[10];
    const float* p2b  = (const float*)d_in[11];
    const float* relW3  = (const float*)d_in[12];
    const float* relb3  = (const float*)d_in[13];
    const float* rootW3 = (const float*)d_in[14];
    const float* l1W  = (const float*)d_in[15];
    const float* l1b  = (const float*)d_in[16];
    const float* l2W  = (const float*)d_in[17];
    const float* l2b  = (const float*)d_in[18];
    float* out = (float*)d_out;

    // ---- workspace layout
    int*  cnt_src = (int*)d_ws;                       // NT
    int*  cnt_dst = cnt_src + NT;                     // NT
    int*  off_src = cnt_dst + NT;                     // NT
    int*  off_dst = off_src + NT;                     // NT
    u16*  srt_dst = (u16*)(off_dst + NT);             // ET u16 (src-sorted, stores local dst)
    u16*  srt_src = srt_dst + ET;                     // ET u16 (dst-sorted, stores local src)
    float* dis = (float*)(srt_src + ET);              // NT
    u32*  xwb  = (u32*)(dis + NT);                    // NT*16 (bf16 x2)
    u32*  hb   = xwb + (size_t)NT * 16;               // NT*16
    u32*  s1b  = hb + (size_t)NT * 16;                // NT*50
    u32*  t1b  = s1b + (size_t)NT * 50;               // NT*50
    float* Cp   = (float*)(t1b + (size_t)NT * 50);    // 4*TB*KP1*232
    float* A1n  = Cp + (size_t)4 * TB * (KP1 * 232);  // TB*KP1*KP1
    float* P1   = A1n + (size_t)TB * KP1 * KP1;       // TB*KP1*HH
    float* P2   = P1 + (size_t)TB * KP1 * HH;         // TB*KP2*HH
    float* A2n  = P2 + (size_t)TB * KP2 * HH;         // TB*100
    float* aux  = A2n + (size_t)TB * 100;             // 1024: den1|loss1|loss2

    k_init<<<4, 256, 0, stream>>>(aux);
    k_sort<<<TB, 512, 0, stream>>>(ei, cnt_src, cnt_dst, off_src, off_dst, srt_dst, srt_src, dis);
    k_xw2<<<NT / 128, 256, 0, stream>>>(x, c1W, (u16*)xwb);
    k_gcng2<<<TB, 512, 0, stream>>>(srt_src, off_dst, cnt_dst, xwb, dis, c1b, hb);
    k_s1m<<<NT / 128, 256, 0, stream>>>(hb, p1W, p1b, cnt_src, (u16*)s1b, aux /*den1*/);
    k_t1g2<<<TB * 2, 512, 0, stream>>>(srt_dst, off_src, cnt_src, s1b, t1b);
    k_gram<<<TB * 4, 512, 0, stream>>>(s1b, t1b, hb, Cp);
    k_fin1<<<TB, 256, 0, stream>>>(Cp, aux /*den1*/, A1n, P1, aux);
    k_s2a<<<TB, 512, 0, stream>>>(A1n, P1, relW2, relb2, rootW2, p2W, p2b, P2, A2n, aux);
    k_s2b<<<TB, 64, 0, stream>>>(P2, A2n, relW3, relb3, rootW3, l1W, l1b, l2W, l2b, out);
    k_loss<<<1, 128, 0, stream>>>(aux, out);
}

// Round 13
// 292.110 us; speedup vs baseline: 1.2106x; 1.2106x over previous
//
#include <hip/hip_runtime.h>
#include <hip/hip_bf16.h>

// Problem constants (match reference)
#define TB   128          // batch B
#define NN   512          // nodes per graph
#define INC  128          // IN_C
#define HH   32           // HID
#define KP1  100          // K1
#define KP2  10           // K2
#define OC   10           // OUT_C
#define EPER 8192         // edges per graph
#define NT   (TB*NN)      // 65536 total nodes
#define ET   (TB*EPER)    // 1048576 total edges
#define ZTR  264          // gram ZT rows: 232 Z-cols + 32 zero pad (partial MFMA tiles)
#define ZTS  40           // ZT row stride in u16 (80 B, 16B-aligned for ds_read_b128)
#define XTS  136          // k_xw2 row stride in u16 (272 B, 16B-aligned)

typedef unsigned int  u32;
typedef unsigned short u16;
typedef __attribute__((ext_vector_type(8))) short bf16x8;   // 8 bf16 = 4 VGPR (MFMA A/B frag)
typedef __attribute__((ext_vector_type(16))) float f32x16;  // MFMA C/D frag

// bf16 helpers (RNE encode; exact decode)
__device__ __forceinline__ u32 bfr(float f) {
    u32 b = __float_as_uint(f);
    return (b + 0x7fffu + ((b >> 16) & 1u)) >> 16;
}
__device__ __forceinline__ u32 pk2(float a, float b) { return bfr(a) | (bfr(b) << 16); }
__device__ __forceinline__ float blo(u32 u) { return __uint_as_float(u << 16); }
__device__ __forceinline__ float bhi(u32 u) { return __uint_as_float(u & 0xffff0000u); }

// ---------------------------------------------------------------- init (aux only)
__global__ void k_init(float* __restrict__ aux) {
    int i = blockIdx.x * 256 + threadIdx.x;
    if (i < 1024) aux[i] = 0.0f;              // den1 / loss1 / loss2 accumulators
}

// ---- fused per-graph counting sort: histogram + scan + scatter + dis, all in LDS
__global__ __launch_bounds__(512) void k_sort(const int* __restrict__ ei,
                                              int* __restrict__ cnt_src, int* __restrict__ cnt_dst,
                                              int* __restrict__ off_src, int* __restrict__ off_dst,
                                              u16* __restrict__ srt_dst, u16* __restrict__ srt_src,
                                              float* __restrict__ dis) {
    __shared__ int hs[NN], hd[NN], ps[NN], pd[NN];              // 8 KB
    __shared__ __align__(16) u16 sdl[EPER], ssl[EPER];          // 32 KB
    int g = blockIdx.x, tid = threadIdx.x, goff = g * NN;
    hs[tid] = 0; hd[tid] = 0;
    __syncthreads();
    const int* es = ei + (size_t)g * EPER;
    const int* ed = ei + ET + (size_t)g * EPER;
    // pass 1: histograms
    for (int e = tid; e < EPER; e += 512) {
        atomicAdd(&hs[es[e] - goff], 1);
        atomicAdd(&hd[ed[e] - goff], 1);
    }
    __syncthreads();
    int vs = hs[tid], vd = hd[tid];
    ps[tid] = vs; pd[tid] = vd; __syncthreads();
    // Hillis-Steele inclusive scan of both histograms
    for (int off = 1; off < NN; off <<= 1) {
        int xa = ps[tid], xb = pd[tid];
        if (tid >= off) { xa += ps[tid - off]; xb += pd[tid - off]; }
        __syncthreads(); ps[tid] = xa; pd[tid] = xb; __syncthreads();
    }
    int eso = ps[tid] - vs, edo = pd[tid] - vd;   // exclusive offsets, graph-local
    cnt_src[goff + tid] = vs;  cnt_dst[goff + tid] = vd;
    off_src[goff + tid] = g * EPER + eso;
    off_dst[goff + tid] = g * EPER + edo;
    dis[goff + tid] = rsqrtf(1.0f + (float)vd);   // +1 self loop
    __syncthreads();
    ps[tid] = eso; pd[tid] = edo;                 // reuse as cursors
    __syncthreads();
    // pass 2: scatter into LDS (u16 local node ids)
    for (int e = tid; e < EPER; e += 512) {
        int s = es[e] - goff, d = ed[e] - goff;
        int p = atomicAdd(&ps[s], 1); sdl[p] = (u16)d;   // src-sorted: store dst
        int q = atomicAdd(&pd[d], 1); ssl[q] = (u16)s;   // dst-sorted: store src
    }
    __syncthreads();
    // coalesced write-out (u32 pairs)
    u32* wd = (u32*)(srt_dst + (size_t)g * EPER);
    u32* ws = (u32*)(srt_src + (size_t)g * EPER);
    const u32* rd = (const u32*)sdl;
    const u32* rs = (const u32*)ssl;
    for (int i = tid; i < EPER / 2; i += 512) { wd[i] = rd[i]; ws[i] = rs[i]; }
}

// ------- xw via MFMA: xw = bf16(x @ conv1_W), block = 128 rows, K=128
__global__ __launch_bounds__(256) void k_xw2(const float* __restrict__ x, const float* __restrict__ W,
                                             u16* __restrict__ xwb) {
    __shared__ u16 sX[128 * XTS];            // 34.8 KB
    __shared__ u16 sW[32 * XTS];             // 8.7 KB
    int tid = threadIdx.x;
    int nbase = blockIdx.x * 128;
    // stage W^T bf16: sW[n][k] = W[k*32+n]
    for (int i = tid; i < INC * HH; i += 256) {
        int k = i >> 5, n = i & 31;
        sW[n * XTS + k] = (u16)bfr(W[i]);
    }
    // stage x rows bf16 (coalesced float4 read, packed u32 LDS write)
    for (int i = tid; i < 128 * 32; i += 256) {
        int r = i >> 5, q = i & 31;
        float4 v = ((const float4*)(x + (size_t)(nbase + r) * INC))[q];
        u32* dst = (u32*)&sX[r * XTS + q * 4];
        dst[0] = pk2(v.x, v.y);
        dst[1] = pk2(v.z, v.w);
    }
    __syncthreads();
    int wave = tid >> 6, lane = tid & 63;
    int lc = lane & 31, half = lane >> 5;
    f32x16 acc;
#pragma unroll
    for (int r = 0; r < 16; r++) acc[r] = 0.f;
#pragma unroll
    for (int kc = 0; kc < 8; kc++) {
        bf16x8 af  = *(const bf16x8*)&sX[(wave * 32 + lc) * XTS + kc * 16 + half * 8];
        bf16x8 bfv = *(const bf16x8*)&sW[lc * XTS + kc * 16 + half * 8];
        acc = __builtin_amdgcn_mfma_f32_32x32x16_bf16(af, bfv, acc, 0, 0, 0);
    }
    // C/D: col n = lc, row m = (r&3)+8*(r>>2)+4*half
#pragma unroll
    for (int r = 0; r < 16; r++) {
        int m = (r & 3) + 8 * (r >> 2) + 4 * half;
        int rowg = nbase + wave * 32 + m;
        xwb[(size_t)rowg * HH + lc] = (u16)bfr(acc[r]);
    }
}

// -------- GCN gather (bf16 xw, u16 indices, XCD-swizzled blocks): hb bf16 only
// 32 blocks/graph; swizzle keeps all blocks of a graph on one XCD (b%8 residue).
__global__ __launch_bounds__(256) void k_gcng(const u16* __restrict__ ssrc, const int* __restrict__ od,
                                              const int* __restrict__ cd, const u32* __restrict__ xwb32,
                                              const float* __restrict__ dis, const float* __restrict__ bias,
                                              u32* __restrict__ hb32) {
    int tid = threadIdx.x;
    int b = blockIdx.x;
    int r8 = b & 7, j = b >> 3;              // j: 0..511
    int g = r8 + 8 * (j & 15);               // graph 0..127, fixed XCD residue
    int chunk = j >> 4;                      // 0..31
    int n = g * NN + chunk * 16 + (tid >> 4), cp = tid & 15;  // cp -> channels 2cp,2cp+1
    int goff = g * NN;
    int base = od[n], cnt = cd[n];
    float dn = dis[n];
    u32 us = xwb32[(size_t)n * 16 + cp];
    float a0 = dn * blo(us), a1 = dn * bhi(us);           // self-loop term
    int i = 0;
    for (; i + 4 <= cnt; i += 4) {
        int s0 = goff + ssrc[base + i],     s1v = goff + ssrc[base + i + 1];
        int s2 = goff + ssrc[base + i + 2], s3  = goff + ssrc[base + i + 3];
        float d0 = dis[s0], d1 = dis[s1v], d2 = dis[s2], d3 = dis[s3];
        u32 u0 = xwb32[(size_t)s0 * 16 + cp];
        u32 u1 = xwb32[(size_t)s1v * 16 + cp];
        u32 u2 = xwb32[(size_t)s2 * 16 + cp];
        u32 u3 = xwb32[(size_t)s3 * 16 + cp];
        a0 += d0 * blo(u0) + d1 * blo(u1) + d2 * blo(u2) + d3 * blo(u3);
        a1 += d0 * bhi(u0) + d1 * bhi(u1) + d2 * bhi(u2) + d3 * bhi(u3);
    }
    for (; i < cnt; i++) {
        int s0 = goff + ssrc[base + i]; float d0 = dis[s0];
        u32 u0 = xwb32[(size_t)s0 * 16 + cp];
        a0 += d0 * blo(u0); a1 += d0 * bhi(u0);
    }
    float v0 = fmaxf(dn * a0 + bias[2 * cp], 0.f);
    float v1 = fmaxf(dn * a1 + bias[2 * cp + 1], 0.f);
    hb32[(size_t)n * 16 + cp] = pk2(v0, v1);
}

// ------- s1 via MFMA: logits = hb @ pool1_W + b, softmax in-register
__global__ __launch_bounds__(256) void k_s1m(const u32* __restrict__ hb32, const float* __restrict__ W,
                                             const float* __restrict__ bias, const int* __restrict__ csrc,
                                             u16* __restrict__ s1b, float* __restrict__ den1) {
    __shared__ u16 sH[128 * ZTS];            // 10.24 KB
    __shared__ u16 sW[128 * ZTS];            // 10.24 KB
    int tid = threadIdx.x;
    int nbase = blockIdx.x * 128;
    // stage W^T bf16: sW[n][k] = W[k*100+n]; coalesced read (n fastest)
    for (int i = tid; i < HH * KP1; i += 256) {
        int k = i / KP1, n = i - k * KP1;
        sW[n * ZTS + k] = (u16)bfr(W[i]);
    }
    // zero pad rows 100..127 (k 0..31 as 16 u32)
    for (int i = tid; i < 28 * 16; i += 256) {
        int n = 100 + (i >> 4), q = i & 15;
        ((u32*)sW)[n * (ZTS / 2) + q] = 0;
    }
    // stage hb rows (coalesced u32)
    for (int i = tid; i < 128 * 16; i += 256) {
        int r = i >> 4, q = i & 15;
        ((u32*)sH)[r * (ZTS / 2) + q] = hb32[(size_t)(nbase + r) * 16 + q];
    }
    __syncthreads();
    int wave = tid >> 6, lane = tid & 63;
    int lc = lane & 31, half = lane >> 5;
    f32x16 acc[4];
#pragma unroll
    for (int t = 0; t < 4; t++)
#pragma unroll
        for (int r = 0; r < 16; r++) acc[t][r] = 0.f;
#pragma unroll
    for (int kc = 0; kc < 2; kc++) {
        bf16x8 af = *(const bf16x8*)&sH[(wave * 32 + lc) * ZTS + kc * 16 + half * 8];
#pragma unroll
        for (int t = 0; t < 4; t++) {
            bf16x8 bfv = *(const bf16x8*)&sW[(t * 32 + lc) * ZTS + kc * 16 + half * 8];
            acc[t] = __builtin_amdgcn_mfma_f32_32x32x16_bf16(af, bfv, acc[t], 0, 0, 0);
        }
    }
    // bias + exp (overwrite acc with e); row sums via lc-butterfly
    float s[16], q[16];
#pragma unroll
    for (int r = 0; r < 16; r++) { s[r] = 0.f; q[r] = 0.f; }
#pragma unroll
    for (int t = 0; t < 4; t++) {
        int ch = t * 32 + lc;
        bool valid = ch < KP1;
        float bv = valid ? bias[ch] : 0.f;
#pragma unroll
        for (int r = 0; r < 16; r++) {
            float ev = valid ? __expf(acc[t][r] + bv) : 0.f;
            acc[t][r] = ev; s[r] += ev; q[r] = fmaf(ev, ev, q[r]);
        }
    }
#pragma unroll
    for (int off = 16; off >= 1; off >>= 1) {
#pragma unroll
        for (int r = 0; r < 16; r++) { s[r] += __shfl_xor(s[r], off); q[r] += __shfl_xor(q[r], off); }
    }
    float inv[16];
#pragma unroll
    for (int r = 0; r < 16; r++) inv[r] = 1.f / s[r];
    // store s1 bf16: row = (reg&3)+8*(reg>>2)+4*half (verified C/D layout), col = t*32+lc
#pragma unroll
    for (int t = 0; t < 4; t++) {
        int ch = t * 32 + lc;
        if (ch < KP1) {
#pragma unroll
            for (int r = 0; r < 16; r++) {
                int lr = (r & 3) + 8 * (r >> 2) + 4 * half;
                int rowg = nbase + wave * 32 + lr;
                s1b[(size_t)rowg * KP1 + ch] = (u16)bfr(acc[t][r] * inv[r]);
            }
        }
    }
    // den1: deg_out[row] * sum(s1^2) per row; lc==0 lanes hold replicated sums
    float contrib = 0.f;
    if (lc == 0) {
#pragma unroll
        for (int r = 0; r < 16; r++) {
            int lr = (r & 3) + 8 * (r >> 2) + 4 * half;
            int rowg = nbase + wave * 32 + lr;
            contrib += (float)csrc[rowg] * q[r] * inv[r] * inv[r];
        }
    }
    contrib += __shfl_xor(contrib, 32);
    if (lane == 0) atomicAdd(&den1[nbase >> 9], contrib);
}

// ------------- t1 gather (bf16, u16 indices, XCD-swizzled): wave per node
// 128 blocks/graph; swizzle keeps all blocks of a graph on one XCD (b%8 residue).
__global__ __launch_bounds__(256) void k_t1g(const u16* __restrict__ sdst, const int* __restrict__ osr,
                                             const int* __restrict__ csr, const u32* __restrict__ s1b32,
                                             u32* __restrict__ t1b32) {
    int tid = threadIdx.x;
    int b = blockIdx.x;
    int r8 = b & 7, j = b >> 3;              // j: 0..2047
    int g = r8 + 8 * (j & 15);               // graph 0..127, fixed XCD residue
    int chunk = j >> 4;                      // 0..127
    int n = g * NN + chunk * 4 + (tid >> 6), lane = tid & 63;
    if (lane >= 50) return;
    int goff = g * NN;
    int base = osr[n], cnt = csr[n];
    float a0 = 0.f, a1 = 0.f;
    int i = 0;
    for (; i + 4 <= cnt; i += 4) {
        int d0 = goff + sdst[base + i],     d1 = goff + sdst[base + i + 1];
        int d2 = goff + sdst[base + i + 2], d3 = goff + sdst[base + i + 3];
        u32 u0 = s1b32[(size_t)d0 * 50 + lane];
        u32 u1 = s1b32[(size_t)d1 * 50 + lane];
        u32 u2 = s1b32[(size_t)d2 * 50 + lane];
        u32 u3 = s1b32[(size_t)d3 * 50 + lane];
        a0 += (blo(u0) + blo(u1)) + (blo(u2) + blo(u3));
        a1 += (bhi(u0) + bhi(u1)) + (bhi(u2) + bhi(u3));
    }
    for (; i < cnt; i++) {
        int d0 = goff + sdst[base + i];
        u32 u0 = s1b32[(size_t)d0 * 50 + lane];
        a0 += blo(u0); a1 += bhi(u0);
    }
    t1b32[(size_t)n * 50 + lane] = pk2(a0, a1);
}

// --- gram via MFMA: C = s1^T [t1 | h | s1] (100 x 232); bf16, 4 slabs.
__global__ __launch_bounds__(512, 4) void k_gram(const u32* __restrict__ s1b32, const u32* __restrict__ t1b32,
                                                 const u32* __restrict__ hb32, float* __restrict__ Cp) {
    __shared__ u16 sZ[2][ZTR * ZTS];         // 2 x 21.1 KB
    int g = blockIdx.x >> 2, slab = blockIdx.x & 3;
    int nbase = g * NN + slab * 128;         // 4 chunks of 32 rows
    int tid = threadIdx.x;
    int wave = tid >> 6, lane = tid & 63;
    int mt = wave & 3;                       // output-row tile: k = mt*32 + row
    int nt0 = (wave >> 2) * 4;               // this wave: nt0..nt0+3
    int lc = lane & 31, half = lane >> 5;

    f32x16 acc[4];
#pragma unroll
    for (int t = 0; t < 4; t++)
#pragma unroll
        for (int r = 0; r < 16; r++) acc[t][r] = 0.f;

    // zero the padding rows of both buffers (channels 232..263)
    for (int i = tid; i < 32 * ZTS; i += 512) {
        int r = 232 + i / ZTS, c = i % ZTS;
        sZ[0][r * ZTS + c] = 0; sZ[1][r * ZTS + c] = 0;
    }
    // ---- stage chunk 0 into buffer 0 (transposing: uint2 = 4 channels of row n)
#pragma unroll
    for (int j = 0; j < 4; j++) {
        int i = tid + j * 512;
        if (i < 32 * 58) {
            int r = i / 58, q = i - r * 58;
            int n = nbase + r;
            uint2 v; int ch0;
            if (q < 25)      { v = ((const uint2*)(t1b32 + (size_t)n * 50))[q];      ch0 = 4 * q; }
            else if (q < 33) { v = ((const uint2*)(hb32  + (size_t)n * 16))[q - 25]; ch0 = 100 + 4 * (q - 25); }
            else             { v = ((const uint2*)(s1b32 + (size_t)n * 50))[q - 33]; ch0 = 132 + 4 * (q - 33); }
            sZ[0][(ch0    ) * ZTS + r] = (u16)(v.x & 0xffffu);
            sZ[0][(ch0 + 1) * ZTS + r] = (u16)(v.x >> 16);
            sZ[0][(ch0 + 2) * ZTS + r] = (u16)(v.y & 0xffffu);
            sZ[0][(ch0 + 3) * ZTS + r] = (u16)(v.y >> 16);
        }
    }
    __syncthreads();

    for (int nt = 0; nt < 4; nt++) {
        // ---- prefetch chunk nt+1 into registers
        uint2 pre[4];
        if (nt < 3) {
#pragma unroll
            for (int j = 0; j < 4; j++) {
                int i = tid + j * 512;
                if (i < 32 * 58) {
                    int r = i / 58, q = i - r * 58;
                    int n = nbase + (nt + 1) * 32 + r;
                    uint2 v;
                    if (q < 25)      v = ((const uint2*)(t1b32 + (size_t)n * 50))[q];
                    else if (q < 33) v = ((const uint2*)(hb32  + (size_t)n * 16))[q - 25];
                    else             v = ((const uint2*)(s1b32 + (size_t)n * 50))[q - 33];
                    pre[j] = v;
                }
            }
        }
        // ---- MFMA on current buffer
        const u16* zb = sZ[nt & 1];
#pragma unroll
        for (int mf = 0; mf < 2; mf++) {
            bf16x8 af = *(const bf16x8*)&zb[(132 + mt * 32 + lc) * ZTS + mf * 16 + half * 8];
#pragma unroll
            for (int t = 0; t < 4; t++) {
                bf16x8 bfv = *(const bf16x8*)&zb[((nt0 + t) * 32 + lc) * ZTS + mf * 16 + half * 8];
                acc[t] = __builtin_amdgcn_mfma_f32_32x32x16_bf16(af, bfv, acc[t], 0, 0, 0);
            }
        }
        // ---- commit prefetch to the other buffer
        if (nt < 3) {
            u16* zo = sZ[(nt + 1) & 1];
#pragma unroll
            for (int j = 0; j < 4; j++) {
                int i = tid + j * 512;
                if (i < 32 * 58) {
                    int r = i / 58, q = i - r * 58;
                    int ch0 = (q < 25) ? (4 * q) : ((q < 33) ? (100 + 4 * (q - 25)) : (132 + 4 * (q - 33)));
                    zo[(ch0    ) * ZTS + r] = (u16)(pre[j].x & 0xffffu);
                    zo[(ch0 + 1) * ZTS + r] = (u16)(pre[j].x >> 16);
                    zo[(ch0 + 2) * ZTS + r] = (u16)(pre[j].y & 0xffffu);
                    zo[(ch0 + 3) * ZTS + r] = (u16)(pre[j].y >> 16);
                }
            }
        }
        __syncthreads();
    }
    // ---- epilogue: C/D layout col=lane&31, row=(reg&3)+8*(reg>>2)+4*(lane>>5)
    float* outp = Cp + ((size_t)slab * TB + g) * (KP1 * 232);
#pragma unroll
    for (int t = 0; t < 4; t++) {
        int l = (nt0 + t) * 32 + lc;
        if (l < 232) {
#pragma unroll
            for (int r = 0; r < 16; r++) {
                int k = mt * 32 + (r & 3) + 8 * (r >> 2) + 4 * half;
                if (k < KP1) outp[k * 232 + l] = acc[t][r];
            }
        }
    }
}

// ---- finalize stage 1: coalesced float4 slab sweep; losses; normalize; P1
__global__ __launch_bounds__(256) void k_fin1(const float* __restrict__ Cp, const float* __restrict__ den1,
                                              float* __restrict__ A1n, float* __restrict__ P1,
                                              float* __restrict__ aux) {
    __shared__ float sA[KP1 * KP1];          // 40 KB
    __shared__ float red[256];
    __shared__ float rs2[256];
    __shared__ float sdv[KP1];
    int g = blockIdx.x, tid = threadIdx.x;
    const float* b0 = Cp + (size_t)g * (KP1 * 232);
    const size_t SLAB = (size_t)TB * (KP1 * 232);
    float ssq = 0.f, trss = 0.f, troa = 0.f;
    // phase 1: sweep 100 rows x 58 float4 cols, coalesced; sum 4 slabs in flight
    for (int idx = tid; idx < KP1 * 58; idx += 256) {
        int k = idx / 58, q = idx - k * 58;
        size_t off = (size_t)k * 232 + q * 4;
        float4 v0 = *(const float4*)(b0 + off);
        float4 v1 = *(const float4*)(b0 + SLAB + off);
        float4 v2 = *(const float4*)(b0 + 2 * SLAB + off);
        float4 v3 = *(const float4*)(b0 + 3 * SLAB + off);
        float4 s;
        s.x = (v0.x + v1.x) + (v2.x + v3.x);
        s.y = (v0.y + v1.y) + (v2.y + v3.y);
        s.z = (v0.z + v1.z) + (v2.z + v3.z);
        s.w = (v0.w + v1.w) + (v2.w + v3.w);
        int c = q * 4;
        if (c < 100) {                        // out_adj block
            *(float4*)&sA[k * KP1 + c] = s;
            if (k >= c && k < c + 4) troa += ((const float*)&s)[k - c];
        } else if (c < 132) {                 // pooled features -> P1 direct
            *(float4*)&P1[((size_t)g * KP1 + k) * HH + (c - 100)] = s;
        } else {                              // ss block: reduce only
            ssq += s.x * s.x + s.y * s.y + s.z * s.z + s.w * s.w;
            int l0 = c - 132;
            if (k >= l0 && k < l0 + 4) trss += ((const float*)&s)[k - l0];
        }
    }
    // block reductions for ssq / trss / troa
    red[tid] = ssq; __syncthreads();
#pragma unroll
    for (int s = 128; s > 0; s >>= 1) { if (tid < s) red[tid] += red[tid + s]; __syncthreads(); }
    float ssqT = red[0]; __syncthreads();
    red[tid] = trss; __syncthreads();
#pragma unroll
    for (int s = 128; s > 0; s >>= 1) { if (tid < s) red[tid] += red[tid + s]; __syncthreads(); }
    float trssT = red[0]; __syncthreads();
    red[tid] = troa; __syncthreads();
#pragma unroll
    for (int s = 128; s > 0; s >>= 1) { if (tid < s) red[tid] += red[tid + s]; __syncthreads(); }
    float troaT = red[0]; __syncthreads();
    // phase 2: row sums (2 threads per row) -> sd
    if (tid < 200) {
        int k = tid >> 1, hf = tid & 1;
        const float* row = &sA[k * KP1 + hf * 50];
        float rs = 0.f;
        for (int l = 0; l < 50; l++) rs += row[l];
        rs2[tid] = rs;
    }
    __syncthreads();
    if (tid < KP1) {
        float rowsum = rs2[2 * tid] + rs2[2 * tid + 1] - sA[tid * KP1 + tid];
        sdv[tid] = sqrtf(rowsum) + 1e-15f;
    }
    if (tid == 0) {
        float ssF = sqrtf(ssqT);
        float o1 = sqrtf(fmaxf(2.f - 2.f * trssT / (ssF * 10.f), 0.f));  // sqrt(K1)=10
        aux[128 + g] = -(troaT / den1[g]) + o1;
    }
    __syncthreads();
    // phase 3: normalize out_adj, coalesced
    for (int i = tid; i < KP1 * KP1; i += 256) {
        int k = i / KP1, l = i - k * KP1;
        A1n[(size_t)g * (KP1 * KP1) + i] = (k == l) ? 0.f : sA[i] / (sdv[k] * sdv[l]);
    }
}

// ------- stage 2a: conv2 + pool2 (per graph); A read from global (L2)
__global__ __launch_bounds__(512) void k_s2a(const float* __restrict__ A1n, const float* __restrict__ P1,
                                             const float* __restrict__ relW, const float* __restrict__ relB,
                                             const float* __restrict__ rootW,
                                             const float* __restrict__ p2W, const float* __restrict__ p2B,
                                             float* __restrict__ P2, float* __restrict__ A2n,
                                             float* __restrict__ aux) {
    __shared__ float sX[KP1 * HH];           // x1p then x2
    __shared__ float sY[KP1 * HH];           // y = A @ x1p
    __shared__ float sS2[KP1 * KP2];
    __shared__ float sT2[KP1 * KP2];
    __shared__ float sA2[100], sB2[100], sdd[10], red[100];
    int g = blockIdx.x, tid = threadIdx.x;
    const float* Ag = A1n + (size_t)g * (KP1 * KP1);
    for (int i = tid; i < KP1 * HH; i += 512) sX[i] = P1[(size_t)g * (KP1 * HH) + i];
    __syncthreads();

    int n = tid >> 2, cq = tid & 3;          // 400 active threads for y / x2
    // y = A @ x1p
    if (tid < 400) {
        float yv[8];
#pragma unroll
        for (int j = 0; j < 8; j++) yv[j] = 0.f;
        for (int mq = 0; mq < 25; mq++) {
            float4 a4 = *(const float4*)&Ag[n * KP1 + mq * 4];
            const float* xb = &sX[(mq * 4) * HH + cq * 8];
            float aa[4] = {a4.x, a4.y, a4.z, a4.w};
#pragma unroll
            for (int mm = 0; mm < 4; mm++) {
                const float* xr = xb + mm * HH;
#pragma unroll
                for (int j = 0; j < 8; j++) yv[j] = fmaf(aa[mm], xr[j], yv[j]);
            }
        }
#pragma unroll
        for (int j = 0; j < 8; j++) sY[n * HH + cq * 8 + j] = yv[j];
    }
    __syncthreads();
    // x2 = relu(y @ relW + relB + x1p @ rootW)
    float x2v[8];
    if (tid < 400) {
#pragma unroll
        for (int j = 0; j < 8; j++) x2v[j] = relB[cq * 8 + j];
        for (int j = 0; j < 32; j++) {
            float yj = sY[n * HH + j];
            float xj = sX[n * HH + j];
            float4 r0 = *(const float4*)&relW[j * 32 + cq * 8];
            float4 r1v = *(const float4*)&relW[j * 32 + cq * 8 + 4];
            float4 q0 = *(const float4*)&rootW[j * 32 + cq * 8];
            float4 q1 = *(const float4*)&rootW[j * 32 + cq * 8 + 4];
            x2v[0] += yj * r0.x + xj * q0.x;  x2v[1] += yj * r0.y + xj * q0.y;
            x2v[2] += yj * r0.z + xj * q0.z;  x2v[3] += yj * r0.w + xj * q0.w;
            x2v[4] += yj * r1v.x + xj * q1.x; x2v[5] += yj * r1v.y + xj * q1.y;
            x2v[6] += yj * r1v.z + xj * q1.z; x2v[7] += yj * r1v.w + xj * q1.w;
        }
    }
    __syncthreads();
    if (tid < 400) {
#pragma unroll
        for (int j = 0; j < 8; j++) sX[n * HH + cq * 8 + j] = fmaxf(x2v[j], 0.f);
    }
    __syncthreads();
    // s2 = softmax(x2 @ p2W + p2B); d2 and den2 partials
    if (tid < KP1) {
        float lg[10];
#pragma unroll
        for (int j = 0; j < 10; j++) lg[j] = p2B[j];
        for (int c = 0; c < 32; c++) {
            float xv = sX[tid * HH + c];
#pragma unroll
            for (int j = 0; j < 10; j++) lg[j] = fmaf(xv, p2W[c * 10 + j], lg[j]);
        }
        float mx = lg[0];
#pragma unroll
        for (int j = 1; j < 10; j++) mx = fmaxf(mx, lg[j]);
        float se = 0.f;
#pragma unroll
        for (int j = 0; j < 10; j++) { lg[j] = __expf(lg[j] - mx); se += lg[j]; }
        float inv = 1.f / se, sq = 0.f;
#pragma unroll
        for (int j = 0; j < 10; j++) { float sv = lg[j] * inv; sS2[tid * 10 + j] = sv; sq += sv * sv; }
        float d2 = 0.f;
        for (int mq = 0; mq < 25; mq++) {
            float4 a4 = *(const float4*)&Ag[tid * KP1 + mq * 4];
            d2 += a4.x + a4.y + a4.z + a4.w;
        }
        red[tid] = d2 * sq;
    }
    __syncthreads();
    // t2 = A @ s2 ; P2 = s2^T x2
    for (int p = tid; p < KP1 * KP2; p += 512) {
        int n2 = p / 10, jj = p % 10;
        float a = 0.f;
        for (int m = 0; m < KP1; m++) a = fmaf(Ag[n2 * KP1 + m], sS2[m * 10 + jj], a);
        sT2[p] = a;
    }
    if (tid < KP2 * HH) {
        int k = tid >> 5, cc = tid & 31;
        float a = 0.f;
        for (int n2 = 0; n2 < KP1; n2++) a = fmaf(sS2[n2 * 10 + k], sX[n2 * HH + cc], a);
        P2[(size_t)g * (KP2 * HH) + tid] = a;
    }
    __syncthreads();
    // oa2, ss2
    if (tid < 100) {
        int k = tid / 10, l = tid % 10;
        float oa = 0.f, ss = 0.f;
        for (int n2 = 0; n2 < KP1; n2++) {
            float sk = sS2[n2 * 10 + k];
            oa = fmaf(sk, sT2[n2 * 10 + l], oa);
            ss = fmaf(sk, sS2[n2 * 10 + l], ss);
        }
        sA2[tid] = oa; sB2[tid] = ss;
    }
    __syncthreads();
    if (tid == 0) {
        float den2 = 0.f;
        for (int i = 0; i < 100; i++) den2 += red[i];
        float troa = 0.f, trss = 0.f, ssq = 0.f;
        for (int k = 0; k < 10; k++) { troa += sA2[k * 10 + k]; trss += sB2[k * 10 + k]; }
        for (int i = 0; i < 100; i++) ssq += sB2[i] * sB2[i];
        float o2 = sqrtf(fmaxf(2.f - 2.f * trss / (sqrtf(ssq) * 3.16227766f), 0.f)); // sqrt(10)
        aux[256 + g] = -(troa / den2) + o2;
    }
    if (tid < 10) {
        float rs = 0.f;
        for (int l = 0; l < 10; l++) if (l != tid) rs += sA2[tid * 10 + l];
        sdd[tid] = sqrtf(rs) + 1e-15f;
    }
    __syncthreads();
    if (tid < 100) {
        int k = tid / 10, l = tid % 10;
        A2n[(size_t)g * 100 + tid] = (k == l) ? 0.f : sA2[tid] / (sdd[k] * sdd[l]);
    }
}

// ---------------- stage 2b: conv3 + mean + MLP head + log_softmax
__global__ __launch_bounds__(64) void k_s2b(const float* __restrict__ P2, const float* __restrict__ A2n,
                                            const float* __restrict__ relW3, const float* __restrict__ relb3,
                                            const float* __restrict__ rootW3,
                                            const float* __restrict__ l1W, const float* __restrict__ l1b,
                                            const float* __restrict__ l2W, const float* __restrict__ l2b,
                                            float* __restrict__ out) {
    __shared__ float sP[KP2 * HH], sA2[100], sY3[KP2 * HH], sG[32], sG1[32], sL[10], sLse;
    int g = blockIdx.x, tid = threadIdx.x;
    for (int i = tid; i < KP2 * HH; i += 64) sP[i] = P2[(size_t)g * (KP2 * HH) + i];
    for (int i = tid; i < 100; i += 64) sA2[i] = A2n[(size_t)g * 100 + i];
    if (tid < 32) sG[tid] = 0.f;
    __syncthreads();
    for (int p = tid; p < KP2 * HH; p += 64) {
        int k = p >> 5, cc = p & 31;
        float a = 0.f;
#pragma unroll
        for (int m = 0; m < 10; m++) a = fmaf(sA2[k * 10 + m], sP[m * HH + cc], a);
        sY3[p] = a;
    }
    __syncthreads();
    for (int p = tid; p < KP2 * HH; p += 64) {
        int k = p >> 5, cc = p & 31;
        float v = relb3[cc];
        for (int j = 0; j < 32; j++)
            v += sY3[k * HH + j] * relW3[j * 32 + cc] + sP[k * HH + j] * rootW3[j * 32 + cc];
        atomicAdd(&sG[cc], v * 0.1f);        // mean over 10 nodes
    }
    __syncthreads();
    if (tid < 32) {
        float v = l1b[tid];
        for (int j = 0; j < 32; j++) v = fmaf(sG[j], l1W[j * 32 + tid], v);
        sG1[tid] = fmaxf(v, 0.f);
    }
    __syncthreads();
    if (tid < 10) {
        float v = l2b[tid];
        for (int j = 0; j < 32; j++) v = fmaf(sG1[j], l2W[j * 10 + tid], v);
        sL[tid] = v;
    }
    __syncthreads();
    if (tid == 0) {
        float mx = sL[0];
        for (int j = 1; j < 10; j++) mx = fmaxf(mx, sL[j]);
        float se = 0.f;
        for (int j = 0; j < 10; j++) se += expf(sL[j] - mx);
        sLse = mx + logf(se);
    }
    __syncthreads();
    if (tid < 10) out[(size_t)g * 10 + tid] = sL[tid] - sLse;
}

// ------------------------------------------------------ total loss
__global__ void k_loss(const float* __restrict__ aux, float* __restrict__ out) {
    __shared__ float red[128];
    int tid = threadIdx.x;
    red[tid] = aux[128 + tid] + aux[256 + tid];
    __syncthreads();
#pragma unroll
    for (int s = 64; s > 0; s >>= 1) { if (tid < s) red[tid] += red[tid + s]; __syncthreads(); }
    if (tid == 0) out[1280] = red[0] * (1.f / 128.f);
}

extern "C" void kernel_launch(void* const* d_in, const int* in_sizes, int n_in,
                              void* d_out, int out_size, void* d_ws, size_t ws_size,
                              hipStream_t stream) {
    const float* x    = (const float*)d_in[0];
    const int*   ei   = (const int*)d_in[1];
    const float* c1W  = (const float*)d_in[3];
    const float* c1b  = (const float*)d_in[4];
    const float* p1W  = (const float*)d_in[5];
    const float* p1b  = (const float*)d_in[6];
    const float* relW2  = (const float*)d_in[7];
    const float* relb2  = (const float*)d_in[8];
    const float* rootW2 = (const float*)d_in[9];
    const float* p2W  = (const float*)d_in[10];
    const float* p2b  = (const float*)d_in[11];
    const float* relW3  = (const float*)d_in[12];
    const float* relb3  = (const float*)d_in[13];
    const float* rootW3 = (const float*)d_in[14];
    const float* l1W  = (const float*)d_in[15];
    const float* l1b  = (const float*)d_in[16];
    const float* l2W  = (const float*)d_in[17];
    const float* l2b  = (const float*)d_in[18];
    float* out = (float*)d_out;

    // ---- workspace layout
    int*  cnt_src = (int*)d_ws;                       // NT
    int*  cnt_dst = cnt_src + NT;                     // NT
    int*  off_src = cnt_dst + NT;                     // NT
    int*  off_dst = off_src + NT;                     // NT
    u16*  srt_dst = (u16*)(off_dst + NT);             // ET u16 (src-sorted, stores local dst)
    u16*  srt_src = srt_dst + ET;                     // ET u16 (dst-sorted, stores local src)
    float* dis = (float*)(srt_src + ET);              // NT
    u32*  xwb  = (u32*)(dis + NT);                    // NT*16 (bf16 x2)
    u32*  hb   = xwb + (size_t)NT * 16;               // NT*16
    u32*  s1b  = hb + (size_t)NT * 16;                // NT*50
    u32*  t1b  = s1b + (size_t)NT * 50;               // NT*50
    float* Cp   = (float*)(t1b + (size_t)NT * 50);    // 4*TB*KP1*232
    float* A1n  = Cp + (size_t)4 * TB * (KP1 * 232);  // TB*KP1*KP1
    float* P1   = A1n + (size_t)TB * KP1 * KP1;       // TB*KP1*HH
    float* P2   = P1 + (size_t)TB * KP1 * HH;         // TB*KP2*HH
    float* A2n  = P2 + (size_t)TB * KP2 * HH;         // TB*100
    float* aux  = A2n + (size_t)TB * 100;             // 1024: den1|loss1|loss2

    k_init<<<4, 256, 0, stream>>>(aux);
    k_sort<<<TB, 512, 0, stream>>>(ei, cnt_src, cnt_dst, off_src, off_dst, srt_dst, srt_src, dis);
    k_xw2<<<NT / 128, 256, 0, stream>>>(x, c1W, (u16*)xwb);
    k_gcng<<<NT / 16, 256, 0, stream>>>(srt_src, off_dst, cnt_dst, xwb, dis, c1b, hb);
    k_s1m<<<NT / 128, 256, 0, stream>>>(hb, p1W, p1b, cnt_src, (u16*)s1b, aux /*den1*/);
    k_t1g<<<NT / 4, 256, 0, stream>>>(srt_dst, off_src, cnt_src, s1b, t1b);
    k_gram<<<TB * 4, 512, 0, stream>>>(s1b, t1b, hb, Cp);
    k_fin1<<<TB, 256, 0, stream>>>(Cp, aux /*den1*/, A1n, P1, aux);
    k_s2a<<<TB, 512, 0, stream>>>(A1n, P1, relW2, relb2, rootW2, p2W, p2b, P2, A2n, aux);
    k_s2b<<<TB, 64, 0, stream>>>(P2, A2n, relW3, relb3, rootW3, l1W, l1b, l2W, l2b, out);
    k_loss<<<1, 128, 0, stream>>>(aux, out);
}